// Round 11
// baseline (235.431 us; speedup 1.0000x reference)
//
#include <hip/hip_runtime.h>

#define SEQ 4096
#define DM 1024
#define NH 16
#define HD 64

typedef __attribute__((ext_vector_type(8))) short short8;
typedef __attribute__((ext_vector_type(4))) short short4v;
typedef __attribute__((ext_vector_type(2))) short short2v;
typedef __attribute__((ext_vector_type(4))) float float4v;
typedef __attribute__((ext_vector_type(4))) int int4v;

__device__ __forceinline__ short f2bf(float f) {
    union { float f; unsigned u; } v; v.f = f;
    unsigned u = v.u;
    return (short)((u + 0x7fffu + ((u >> 16) & 1u)) >> 16);
}
// pack two fp32 -> dword of two round-half-up bf16 (3 VALU: add, add, perm)
__device__ __forceinline__ int pk2bf(float a, float b) {
    union { float f; unsigned u; } x, y; x.f = a; y.f = b;
    return (int)__builtin_amdgcn_perm(y.u + 0x8000u, x.u + 0x8000u, 0x07060302u);
}

__device__ __forceinline__ void gload_lds16(const void* g, void* l) {
    __builtin_amdgcn_global_load_lds(
        (const __attribute__((address_space(1))) void*)g,
        (__attribute__((address_space(3))) void*)l, 16, 0, 0);
}

// ---------- prep: cast x -> bf16  +  transpose/cast both weights (one launch) ----------
__global__ __launch_bounds__(256) void prep_kernel(const float* __restrict__ x,
                                                   const float* __restrict__ Wqkv,
                                                   const float* __restrict__ Wout,
                                                   short* __restrict__ xb,
                                                   short* __restrict__ wqkvT,
                                                   short* __restrict__ woutT,
                                                   float qscale) {
    __shared__ float tile[32][33];
    int id = blockIdx.x;
    int tid = threadIdx.x;
    if (id < 4096) {
        int i = id * 256 + tid;
        float4v v = ((const float4v*)x)[i];
        short4v o;
        o[0] = f2bf(v[0]); o[1] = f2bf(v[1]); o[2] = f2bf(v[2]); o[3] = f2bf(v[3]);
        ((short4v*)xb)[i] = o;
        return;
    }
    const float* in; short* outp; int H, W, sr; float sc; int gx, gy;
    if (id < 4096 + 3072) {
        int i2 = id - 4096;
        in = Wqkv; outp = wqkvT; H = DM; W = 3 * DM; sr = DM; sc = qscale;
        gx = i2 % 96; gy = i2 / 96;
    } else {
        int i3 = id - 7168;
        in = Wout; outp = woutT; H = DM; W = DM; sr = 0; sc = 1.0f;
        gx = i3 % 32; gy = i3 / 32;
    }
    int bx = gx * 32, by = gy * 32;
    int tx = tid & 31, ty = tid >> 5;
#pragma unroll
    for (int i = 0; i < 32; i += 8)
        tile[ty + i][tx] = in[(by + ty + i) * W + bx + tx];
    __syncthreads();
#pragma unroll
    for (int i = 0; i < 32; i += 8) {
        int orow = bx + ty + i;
        float s = (orow < sr) ? sc : 1.0f;
        outp[orow * H + by + tx] = f2bf(tile[tx][ty + i] * s);
    }
}

// ------------- GEMM1: xb[4096,1024] x wqkvT[3072,1024] -> qkv (Q,K) + vt (V, swizzled) --
__global__ __launch_bounds__(256) void gemm_qkv(const short* __restrict__ A,
                                                const short* __restrict__ BT,
                                                short* __restrict__ C,
                                                short* __restrict__ vt) {
    const int K = DM, N = 3 * DM;
    __shared__ short As[128 * 32];
    __shared__ short Bs[128 * 32];
    __shared__ short Vt[64 * 136];
    int tid  = threadIdx.x;
    int m0   = blockIdx.y * 128;
    int n0   = blockIdx.x * 128;
    int w    = tid >> 6, lane = tid & 63;
    int wm   = w >> 1,  wn   = w & 1;
    int quad = lane >> 4, l15 = lane & 15;
    int srow = lane >> 2;
    int scol = (lane & 3) * 8;

    float4v acc[4][4];
#pragma unroll
    for (int mi = 0; mi < 4; mi++)
#pragma unroll
        for (int ni = 0; ni < 4; ni++)
            acc[mi][ni] = {0.f, 0.f, 0.f, 0.f};

    for (int k0 = 0; k0 < K; k0 += 32) {
        __syncthreads();
#pragma unroll
        for (int t = 0; t < 2; t++) {
            int chunk = w * 2 + t;
            int r = chunk * 16 + srow;
            gload_lds16(&A[(m0 + r) * K + k0 + scol], &As[chunk * 16 * 32]);
            gload_lds16(&BT[(n0 + r) * K + k0 + scol], &Bs[chunk * 16 * 32]);
        }
        __syncthreads();
        short8 a[4], b[4];
#pragma unroll
        for (int mi = 0; mi < 4; mi++)
            a[mi] = *(const short8*)&As[(wm * 64 + mi * 16 + l15) * 32 + quad * 8];
#pragma unroll
        for (int ni = 0; ni < 4; ni++)
            b[ni] = *(const short8*)&Bs[(wn * 64 + ni * 16 + l15) * 32 + quad * 8];
#pragma unroll
        for (int mi = 0; mi < 4; mi++)
#pragma unroll
            for (int ni = 0; ni < 4; ni++)
                acc[mi][ni] = __builtin_amdgcn_mfma_f32_16x16x32_bf16(a[mi], b[ni], acc[mi][ni], 0, 0, 0);
    }

    if (n0 < 2 * DM) {
#pragma unroll
        for (int mi = 0; mi < 4; mi++)
#pragma unroll
            for (int ni = 0; ni < 4; ni++)
#pragma unroll
                for (int r = 0; r < 4; r++) {
                    int row = m0 + wm * 64 + mi * 16 + quad * 4 + r;
                    int col = n0 + wn * 64 + ni * 16 + l15;
                    C[row * N + col] = f2bf(acc[mi][ni][r]);
                }
    } else {
#pragma unroll
        for (int half = 0; half < 2; half++) {
            __syncthreads();
            if (wn == half) {
#pragma unroll
                for (int mi = 0; mi < 4; mi++)
#pragma unroll
                    for (int ni = 0; ni < 4; ni++) {
                        int drow  = ni * 16 + l15;
                        int sbase = wm * 64 + mi * 16 + quad * 4;
                        short4v pv;
#pragma unroll
                        for (int r = 0; r < 4; r++)
                            pv[r] = f2bf(acc[mi][ni][r]);
                        *(short4v*)&Vt[drow * 136 + sbase] = pv;
                    }
            }
            __syncthreads();
#pragma unroll
            for (int p = 0; p < 4; p++) {
                int drow  = p * 16 + (tid >> 4);
                int chunk = tid & 15;
                int sl    = chunk * 8;
                int sg    = m0 + sl;
                int swz0  = (sg & ~31) | ((sg & 12) << 1) | ((sg & 16) >> 2);
                int sg1   = sg + 4;
                int swz1  = (sg1 & ~31) | ((sg1 & 12) << 1) | ((sg1 & 16) >> 2);
                int dcolg = n0 - 2 * DM + half * 64 + drow;
                short4v a0 = *(const short4v*)&Vt[drow * 136 + sl];
                short4v a1 = *(const short4v*)&Vt[drow * 136 + sl + 4];
                *(short4v*)&vt[dcolg * SEQ + swz0] = a0;
                *(short4v*)&vt[dcolg * SEQ + swz1] = a1;
            }
        }
    }
}

// ------------- GEMM2: 64x128 tile -------------
__global__ __launch_bounds__(256) void gemm_bt64(const short* __restrict__ A,
                                                 const short* __restrict__ BT,
                                                 float* __restrict__ C,
                                                 int M, int N, int K) {
    __shared__ short As[64 * 32];
    __shared__ short Bs[128 * 32];
    int tid  = threadIdx.x;
    int m0   = blockIdx.y * 64;
    int n0   = blockIdx.x * 128;
    int w    = tid >> 6, lane = tid & 63;
    int wm   = w >> 1,  wn   = w & 1;
    int quad = lane >> 4, l15 = lane & 15;
    int srow = lane >> 2;
    int scol = (lane & 3) * 8;

    float4v acc[2][4];
#pragma unroll
    for (int mi = 0; mi < 2; mi++)
#pragma unroll
        for (int ni = 0; ni < 4; ni++)
            acc[mi][ni] = {0.f, 0.f, 0.f, 0.f};

    for (int k0 = 0; k0 < K; k0 += 32) {
        __syncthreads();
        {
            int r = w * 16 + srow;
            gload_lds16(&A[(m0 + r) * K + k0 + scol], &As[w * 16 * 32]);
        }
#pragma unroll
        for (int t = 0; t < 2; t++) {
            int chunk = w * 2 + t;
            int r = chunk * 16 + srow;
            gload_lds16(&BT[(n0 + r) * K + k0 + scol], &Bs[chunk * 16 * 32]);
        }
        __syncthreads();
        short8 a[2], b[4];
#pragma unroll
        for (int mi = 0; mi < 2; mi++)
            a[mi] = *(const short8*)&As[(wm * 32 + mi * 16 + l15) * 32 + quad * 8];
#pragma unroll
        for (int ni = 0; ni < 4; ni++)
            b[ni] = *(const short8*)&Bs[(wn * 64 + ni * 16 + l15) * 32 + quad * 8];
#pragma unroll
        for (int mi = 0; mi < 2; mi++)
#pragma unroll
            for (int ni = 0; ni < 4; ni++)
                acc[mi][ni] = __builtin_amdgcn_mfma_f32_16x16x32_bf16(a[mi], b[ni], acc[mi][ni], 0, 0, 0);
    }

#pragma unroll
    for (int mi = 0; mi < 2; mi++)
#pragma unroll
        for (int ni = 0; ni < 4; ni++)
#pragma unroll
            for (int r = 0; r < 4; r++) {
                int row = m0 + wm * 32 + mi * 16 + quad * 4 + r;
                int col = n0 + wn * 64 + ni * 16 + l15;
                C[row * N + col] = acc[mi][ni][r];
            }
}

// ------------- flash attention: DMA double-buffered K/V, ONE barrier/tile -------------
// R10 found attn's missing ~1.2k cyc/tile is the 2nd __syncthreads' vmcnt(0) drain issued
// right after the prefetch loads. Fix: global_load_lds DMA into LDS buf[nxt] at the TOP
// of iteration t (t+1's tile), compute ~1k cyc from buf[cur], single barrier at bottom --
// drain lands after compute, DMA latency hidden. DMA needs contiguous 1KB segments, so
// bank safety comes from an XOR chunk swizzle (pos = chunk ^ (row&7)) applied on the
// per-lane SOURCE address; read side folds the XOR into immediates (m97-class pattern).
// 64-row blocks (2 waves x 32 rows), grid 16x64 = 4 blocks/CU: same wave-tile total as
// 128-row blocks (R3 lesson), but 4 independent barrier groups/CU. Co-resident t-sets
// {63-j, j, 47-j, 16+j} sum 126 (balanced), heavy first. XCD head pinning kept.
__global__ __launch_bounds__(128) void attn_kernel(const short* __restrict__ qkv,
                                                   const short* __restrict__ vtp,
                                                   short* __restrict__ aout) {
    __shared__ short Ks[2][64 * 64];
    __shared__ short Vs[2][64 * 64];
    int h = blockIdx.x;              // 0..15 -> XCD = h%8
    int y = blockIdx.y;              // 0..63
    int j = y & 15, g = y >> 4;
    int t = (g == 0) ? 63 - j : (g == 1) ? j : (g == 2) ? 47 - j : 16 + j;
    int q0 = t * 64;
    int tid = threadIdx.x;
    int w = tid >> 6, lane = tid & 63;
    int quad = lane >> 4, l15 = lane & 15;
    int x7 = l15 & 7;
    int qw = q0 + w * 32;
    int sr = lane >> 3;              // row within 8-row DMA segment
    int sc = (lane & 7) ^ (sr & 7);  // XOR-swizzled source chunk

    const short* Kg = qkv + DM + h * HD;
    const short* Vg = vtp + (h * HD) * SEQ;

    // Q fragments (B-operand of S^T MFMA); Q pre-scaled by 0.125*log2e
    short8 aq[2][2];
#pragma unroll
    for (int mi = 0; mi < 2; mi++)
#pragma unroll
        for (int kk = 0; kk < 2; kk++)
            aq[mi][kk] = *(const short8*)&qkv[(qw + mi * 16 + l15) * (3 * DM) + h * HD + kk * 32 + quad * 8];

    float lp[2] = {0.f, 0.f};
    float4v o[2][4];
#pragma unroll
    for (int mi = 0; mi < 2; mi++)
#pragma unroll
        for (int dt = 0; dt < 4; dt++)
            o[mi][dt] = {0.f, 0.f, 0.f, 0.f};

    int nT = t + 1;

    // tile 0 DMA (wave stages its 32 rows of K s-rows and V d-rows: 4 segs of 8 rows)
#pragma unroll
    for (int seg = 0; seg < 4; seg++) {
        int rb = w * 32 + seg * 8;
        gload_lds16(&Kg[(rb + sr) * (3 * DM) + sc * 8], &Ks[0][rb * 64]);
        gload_lds16(&Vg[(rb + sr) * SEQ + sc * 8], &Vs[0][rb * 64]);
    }
    __syncthreads();

    for (int tt = 0; tt < nT; tt++) {
        int cur = tt & 1;
        if (tt + 1 < nT) {
            int sn = (tt + 1) * 64;
#pragma unroll
            for (int seg = 0; seg < 4; seg++) {
                int rb = w * 32 + seg * 8;
                gload_lds16(&Kg[(sn + rb + sr) * (3 * DM) + sc * 8], &Ks[cur ^ 1][rb * 64]);
                gload_lds16(&Vg[(rb + sr) * SEQ + sn + sc * 8], &Vs[cur ^ 1][rb * 64]);
            }
        }
        const short* Kc = Ks[cur];
        const short* Vc = Vs[cur];
        short8 kc[8], vc[8];
#pragma unroll
        for (int ni = 0; ni < 4; ni++)
#pragma unroll
            for (int kk = 0; kk < 2; kk++)
                kc[ni * 2 + kk] = *(const short8*)&Kc[(ni * 16 + l15) * 64 + ((quad + 4 * kk) ^ x7) * 8];
#pragma unroll
        for (int dt = 0; dt < 4; dt++)
#pragma unroll
            for (int pr = 0; pr < 2; pr++)
                vc[dt * 2 + pr] = *(const short8*)&Vc[(dt * 16 + l15) * 64 + ((quad + 4 * pr) ^ x7) * 8];

        int s0 = tt * 64;
        // S^T = K Q^T : [mi][ni] holds S[q=qw+mi*16+l15][s=s0+ni*16+quad*4+r]
        float4v s[2][4];
#pragma unroll
        for (int mi = 0; mi < 2; mi++)
#pragma unroll
            for (int ni = 0; ni < 4; ni++) {
                float4v a = {0.f, 0.f, 0.f, 0.f};
#pragma unroll
                for (int kk = 0; kk < 2; kk++)
                    a = __builtin_amdgcn_mfma_f32_16x16x32_bf16(kc[ni * 2 + kk], aq[mi][kk], a, 0, 0, 0);
                s[mi][ni] = a;
            }

        bool diag = (s0 + 63 > qw);
        short8 pa[2][2];
#pragma unroll
        for (int mi = 0; mi < 2; mi++) {
            int qrow = qw + mi * 16 + l15;
#pragma unroll
            for (int ni = 0; ni < 4; ni++) {
#pragma unroll
                for (int r = 0; r < 4; r++) {
                    float p = __builtin_amdgcn_exp2f(s[mi][ni][r]);
                    if (diag) {
                        int scol = s0 + ni * 16 + quad * 4 + r;
                        p = (scol <= qrow) ? p : 0.f;
                    }
                    lp[mi] += p;
                    s[mi][ni][r] = p;
                }
            }
#pragma unroll
            for (int pr = 0; pr < 2; pr++) {
                int4v wpk;
                wpk[0] = pk2bf(s[mi][2 * pr][0], s[mi][2 * pr][1]);
                wpk[1] = pk2bf(s[mi][2 * pr][2], s[mi][2 * pr][3]);
                wpk[2] = pk2bf(s[mi][2 * pr + 1][0], s[mi][2 * pr + 1][1]);
                wpk[3] = pk2bf(s[mi][2 * pr + 1][2], s[mi][2 * pr + 1][3]);
                pa[mi][pr] = *(short8*)&wpk;
            }
        }
#pragma unroll
        for (int mi = 0; mi < 2; mi++)
#pragma unroll
            for (int dt = 0; dt < 4; dt++)
#pragma unroll
                for (int pr = 0; pr < 2; pr++)
                    o[mi][dt] = __builtin_amdgcn_mfma_f32_16x16x32_bf16(pa[mi][pr], vc[dt * 2 + pr], o[mi][dt], 0, 0, 0);
        __syncthreads();   // single barrier: buf[nxt] DMA done + all reads of buf[cur] done
    }

#pragma unroll
    for (int mi = 0; mi < 2; mi++) {
        lp[mi] += __shfl_xor(lp[mi], 16, 64);
        lp[mi] += __shfl_xor(lp[mi], 32, 64);
    }
#pragma unroll
    for (int mi = 0; mi < 2; mi++)
#pragma unroll
        for (int r = 0; r < 4; r++) {
            float lr = __shfl(lp[mi], quad * 4 + r, 16);
            float inv = 1.0f / lr;
#pragma unroll
            for (int dt = 0; dt < 4; dt++) {
                float v = o[mi][dt][r] * inv;
                aout[(qw + mi * 16 + quad * 4 + r) * DM + h * HD + dt * 16 + l15] = f2bf(v);
            }
        }
}

extern "C" void kernel_launch(void* const* d_in, const int* in_sizes, int n_in,
                              void* d_out, int out_size, void* d_ws, size_t ws_size,
                              hipStream_t stream) {
    const float* x    = (const float*)d_in[0];
    const float* Wqkv = (const float*)d_in[1];
    const float* Wout = (const float*)d_in[2];
    float* out = (float*)d_out;

    char* ws = (char*)d_ws;
    short* xb    = (short*)(ws);                                 // 4096x1024 bf16   (8 MB)
    short* wqkvT = (short*)(ws + 8388608);                       // 3072x1024 bf16   (6 MB)
    short* woutT = (short*)(ws + 8388608 + 6291456);             // 1024x1024 bf16   (2 MB)
    short* qkv   = (short*)(ws + 16777216);                      // 4096x3072 bf16   (24 MB; V cols unused)
    short* vt    = (short*)(ws + 16777216 + 25165824);           // 16x64x4096 bf16  (8 MB, swizzled)
    short* ao    = (short*)(ws + 16777216 + 25165824 + 8388608); // 4096x1024 bf16   (8 MB)

    const float SC = 0.18033688011112042f;  // (1/sqrt(64)) * log2(e)

    prep_kernel<<<8192, 256, 0, stream>>>(x, Wqkv, Wout, xb, wqkvT, woutT, SC);

    gemm_qkv<<<dim3(3 * DM / 128, SEQ / 128), 256, 0, stream>>>(xb, wqkvT, qkv, vt);

    attn_kernel<<<dim3(NH, SEQ / 64), 128, 0, stream>>>(qkv, vt, ao);

    gemm_bt64<<<dim3(DM / 128, SEQ / 64), 256, 0, stream>>>(ao, woutT, out, SEQ, DM, DM);
}